// Round 2
// baseline (6020.201 us; speedup 1.0000x reference)
//
#include <hip/hip_runtime.h>
#include <math.h>

#define PI_F 3.14159265358979323846f

typedef _Float16 half8 __attribute__((ext_vector_type(8)));
typedef _Float16 half4 __attribute__((ext_vector_type(4)));
typedef float f32x4 __attribute__((ext_vector_type(4)));

#define MFMA(a, b, c) __builtin_amdgcn_mfma_f32_16x16x32_f16(a, b, c, 0, 0, 0)
#define OFF_CAT 49152   // halfs: wcat starts after whh0 (3*128*128)

__device__ __forceinline__ float rcp_fast(float x) { return __builtin_amdgcn_rcpf(x); }
__device__ __forceinline__ float sigmoid_f(float x) {
    float e = __expf(-x);
    return rcp_fast(1.0f + e);
}
__device__ __forceinline__ float tanh_f(float x) {
    float ax = fabsf(x);
    float e  = __expf(-2.0f * ax);
    float t  = (1.0f - e) * rcp_fast(1.0f + e);
    return x >= 0.0f ? t : -t;
}

// Prep: f16 weights; concat [w_ih1|w_hh1] along K for layer 1.
__global__ void prep_kernel(const float* __restrict__ whh0,
                            const float* __restrict__ wih1,
                            const float* __restrict__ whh1,
                            _Float16* __restrict__ wsp) {
    int i = blockIdx.x * 256 + threadIdx.x;
    if (i < 49152) wsp[i] = (_Float16)whh0[i];
    if (i < 98304) {
        int n = i >> 8, k = i & 255;
        float v = (k < 128) ? wih1[(n << 7) + k] : whh1[(n << 7) + k - 128];
        wsp[OFF_CAT + i] = (_Float16)v;
    }
}

// 512-thread blocks, 32 elements each -> LDS ~69 KB -> 2 blocks/CU (two
// independent barrier domains per CU; when one block drains its barrier the
// other feeds the pipes). Each wave covers 32 dims (2 MFMA row-blocks), so
// 4 waves per layer read each h plane (half the LDS read traffic of the
// previous 8-wave/16-dim split).
//
// h planes (32 elems) in MFMA-B-frag chunk order, double-buffered by parity:
//   plane[buf][(kc*2 + n)*512 + (qd*16 + l4)*8 + j] = h[e=n*16+l4][dim=32kc+8qd+j]
// Pipeline (tick p): L0 waves (0-3) compute h0(p): read h0[prv], write h0[cur].
//                    L1 waves (4-7) compute h1(p-1): read h0[prv] + h1[cur], write h1[prv].
//                    Head (waves 0-1) for step p-2: read h1[cur]. One barrier per tick.
//
// Weights are streamed from global (L2-hot, 288 KB shared across the XCD)
// every tick, never register-resident (16 waves/CU -> 128 unified regs/wave).
// L1 is two passes (R/Z then N) to keep live acc+weight regs under the cap.
// The opaque `wz` defeats LICM so weight loads stay inside the tick loop.

__global__ void __launch_bounds__(512, 4) rnn_wf_pipe(
    const int*   __restrict__ x,
    const float* __restrict__ w_ih0,
    const float* __restrict__ w_lin,
    const float* __restrict__ b_lin,
    const _Float16* __restrict__ wsp,
    float*       __restrict__ out,
    int nbatch)
{
    __shared__ _Float16 h0hi[2][4096], h0lo[2][4096];
    __shared__ _Float16 h1hi[2][4096], h1lo[2][4096];
    __shared__ float gi0T[2][3][128];          // [prev-bit][gate][dim]
    __shared__ float wlinT[256];               // w_lin flat
    __shared__ unsigned long long bmk[32];     // per-element bit mask

    const int t    = threadIdx.x;
    const int wv   = t >> 6;                   // 0..7
    const int l4   = t & 15;
    const int q    = (t >> 4) & 3;
    const int wvd  = wv & 3;                   // dim-slot within layer group (32 dims each)
    const int eb   = blockIdx.x * 32;

    // ---- init LDS ----
    for (int i = t; i < 4096; i += 512) {      // 4096 ints = 2 bufs x 4096 halfs per array
        ((int*)h0hi)[i] = 0; ((int*)h0lo)[i] = 0;
        ((int*)h1hi)[i] = 0; ((int*)h1lo)[i] = 0;
    }
    for (int i = t; i < 768; i += 512) {
        int b = i / 384, rem = i - b * 384;
        ((float*)gi0T)[b * 384 + rem] = w_ih0[rem * 2 + b];
    }
    if (t < 256) wlinT[t] = w_lin[t];
    if (t < 128) {   // bit masks: thread t -> element t>>2, quarter t&3
        int el = t >> 2, qq = t & 3;
        int eg = eb + el; if (eg >= nbatch) eg = nbatch - 1;
        const int* xr = x + (size_t)eg * 64 + qq * 16;
        unsigned long long m = 0ull;
#pragma unroll
        for (int i = 0; i < 16; ++i)
            m |= ((unsigned long long)((unsigned)(xr[i] + 1) >> 1)) << (qq * 16 + i);
        m |= __shfl_xor(m, 1);
        m |= __shfl_xor(m, 2);
        if (qq == 0) bmk[el] = m;
    }

    const int lo8 = ((q << 4) + l4) << 3;      // B-frag lane chunk offset (halfs)
    // epilogue half4 offset: + rb*256 + n*512
    const int epb = wvd * 1024 + (q >> 1) * 128 + l4 * 8 + 4 * (q & 1);

    __syncthreads();

    if (wv < 4) {
        // ================= Layer-0 + head waves =================
        // per-lane weight base (g=0, rb=0, kc=0): row = 32*wvd + l4, k-offset 8q
        const _Float16* wbase0 = wsp + (size_t)(32 * wvd + l4) * 128 + 8 * q;

        const float bl0 = b_lin[0], bl1 = b_lin[1];
        const int eh = (wv << 4) + l4;         // head element (wv<2), q-replicated
        float amp = 1.0f, phs = 0.0f, nu = 0.0f, nd = 0.0f;
        unsigned wz = 0;

        for (int tick = 0; tick < 66; ++tick) {
            const int cur = tick & 1, prv = cur ^ 1;
            if (tick < 64) {
                // h0(tick) = GRU0(onehot(bit(tick-1)), h0(tick-1))
                asm volatile("" : "+v"(wz));           // defeat LICM on weight loads
                const _Float16* wp = wbase0 + wz;

                f32x4 acc[3][2][2];                    // [gate][rb][n]
#pragma unroll
                for (int g = 0; g < 3; ++g)
#pragma unroll
                    for (int rb = 0; rb < 2; ++rb)
#pragma unroll
                        for (int n = 0; n < 2; ++n)
                            acc[g][rb][n] = (f32x4){0,0,0,0};
#pragma unroll
                for (int kc = 0; kc < 4; ++kc) {
                    half8 w[3][2];
#pragma unroll
                    for (int g = 0; g < 3; ++g)
#pragma unroll
                        for (int rb = 0; rb < 2; ++rb)
                            w[g][rb] = *(const half8*)(wp + g * 16384 + rb * 2048 + kc * 32);
#pragma unroll
                    for (int n = 0; n < 2; ++n) {
                        const int cb = (kc * 2 + n) * 512 + lo8;
                        half8 hh = *(const half8*)&h0hi[prv][cb];
                        half8 hl = *(const half8*)&h0lo[prv][cb];
#pragma unroll
                        for (int rb = 0; rb < 2; ++rb) {
                            acc[0][rb][n] = MFMA(w[0][rb], hh, acc[0][rb][n]);
                            acc[1][rb][n] = MFMA(w[1][rb], hh, acc[1][rb][n]);
                            acc[2][rb][n] = MFMA(w[2][rb], hh, acc[2][rb][n]);
                            acc[0][rb][n] = MFMA(w[0][rb], hl, acc[0][rb][n]);
                            acc[1][rb][n] = MFMA(w[1][rb], hl, acc[1][rb][n]);
                            acc[2][rb][n] = MFMA(w[2][rb], hl, acc[2][rb][n]);
                        }
                    }
                }
#pragma unroll
                for (int n = 0; n < 2; ++n) {
                    const int e = n * 16 + l4;
                    int pb = 0;
                    if (tick > 0) pb = (int)((bmk[e] >> (tick - 1)) & 1ull);
                    const float* gp = &gi0T[pb][0][0];
#pragma unroll
                    for (int rb = 0; rb < 2; ++rb) {
                        f32x4 giR = {0,0,0,0}, giZ = {0,0,0,0}, giN = {0,0,0,0};
                        if (tick > 0) {
                            const int dg = 32 * wvd + 16 * rb + 4 * q;
                            giR = *(const f32x4*)(gp + dg);
                            giZ = *(const f32x4*)(gp + 128 + dg);
                            giN = *(const f32x4*)(gp + 256 + dg);
                        }
                        const int ep = epb + rb * 256 + n * 512;
                        half4 hph = *(const half4*)&h0hi[prv][ep];
                        half4 hpl = *(const half4*)&h0lo[prv][ep];
                        half4 nh, nl;
#pragma unroll
                        for (int r = 0; r < 4; ++r) {
                            float rr = sigmoid_f(giR[r] + acc[0][rb][n][r]);
                            float zz = sigmoid_f(giZ[r] + acc[1][rb][n][r]);
                            float nn = tanh_f(giN[r] + rr * acc[2][rb][n][r]);
                            float hprev = (float)hph[r] + (float)hpl[r];
                            float hn = (1.0f - zz) * nn + zz * hprev;
                            _Float16 hi = (_Float16)hn;
                            nh[r] = hi;
                            nl[r] = (_Float16)(hn - (float)hi);
                        }
                        *(half4*)&h0hi[cur][ep] = nh;
                        *(half4*)&h0lo[cur][ep] = nl;
                    }
                }
            }
            if (wv < 2 && tick >= 2) {
                // head for step s = tick-2; h1(s) lives in buf s&1 == tick&1 == cur
                const int s = tick - 2;
                float l0 = 0.0f, l1 = 0.0f;
#pragma unroll
                for (int qq = 0; qq < 4; ++qq) {   // this q-copy handles kc = q
                    const int cb = (q * 2 + wv) * 512 + (qq * 16 + l4) * 8;
                    half8 hh = *(const half8*)&h1hi[cur][cb];
                    half8 hl = *(const half8*)&h1lo[cur][cb];
                    const float* wp = &wlinT[32 * q + 8 * qq];
#pragma unroll
                    for (int j = 0; j < 8; ++j) {
                        float hv = (float)hh[j] + (float)hl[j];
                        l0 = fmaf(hv, wp[j], l0);
                        l1 = fmaf(hv, wp[128 + j], l1);
                    }
                }
                l0 += __shfl_xor(l0, 16); l0 += __shfl_xor(l0, 32); l0 += bl0;
                l1 += __shfl_xor(l1, 16); l1 += __shfl_xor(l1, 32); l1 += bl1;

                float p0 = sigmoid_f(l0 - l1);
                float p1 = sigmoid_f(l1 - l0);
                float y0 = sqrtf(p0), y1 = sqrtf(p1);
                float ph0 = PI_F * l0 * rcp_fast(1.0f + fabsf(l0));
                float ph1 = PI_F * l1 * rcp_fast(1.0f + fabsf(l1));

                int bit = (int)((bmk[eh] >> s) & 1ull);
                bool is_even = (s & 1) == 0;
                float num   = is_even ? nu : nd;
                float lower = -16.0f + (float)(s >> 1);
                float occ   = (num < 16.0f) ? 1.0f : 0.0f;
                float unocc = (num > lower) ? 1.0f : 0.0f;
                if (s >= 16) {
                    float m0 = y0 * unocc, m1 = y1 * occ;
                    float nrm = fmaxf(sqrtf(m0 * m0 + m1 * m1), 1e-12f);
                    float rn  = rcp_fast(nrm);
                    y0 = m0 * rn; y1 = m1 * rn;
                }
                if (is_even) nu += (float)bit; else nd += (float)bit;
                amp *= bit ? y1 : y0;
                phs += bit ? ph1 : ph0;
            }
            __syncthreads();
        }

        if (wv < 2 && q == 0) {
            int eg = eb + eh;
            if (eg < nbatch) {
                float s, c;
                sincosf(phs, &s, &c);
                out[eg]          = amp * c;
                out[nbatch + eg] = amp * s;
            }
        }
    } else {
        // ================= Layer-1 waves =================
        // per-lane weight base (g=0, rb=0, kc=0): row stride 256 halfs (K=256 concat)
        const _Float16* wbase1 = wsp + OFF_CAT + (size_t)(32 * wvd + l4) * 256 + 8 * q;
        unsigned wz = 0;

        for (int tick = 0; tick < 66; ++tick) {
            const int cur = tick & 1, prv = cur ^ 1;
            if (tick >= 1 && tick < 65) {
                // h1(tick-1) = GRU1(h0(tick-1), h1(tick-2)): read h0[prv], h1[cur]; write h1[prv]
                asm volatile("" : "+v"(wz));           // defeat LICM on weight loads
                const _Float16* wp = wbase1 + wz;

                // ---- pass A: R and Z gates ----
                f32x4 aR[2][2], aZ[2][2];              // [rb][n]
#pragma unroll
                for (int rb = 0; rb < 2; ++rb)
#pragma unroll
                    for (int n = 0; n < 2; ++n) {
                        aR[rb][n] = (f32x4){0,0,0,0};
                        aZ[rb][n] = (f32x4){0,0,0,0};
                    }
#pragma unroll
                for (int kc = 0; kc < 8; ++kc) {
                    half8 wR0 = *(const half8*)(wp +                kc * 32);
                    half8 wR1 = *(const half8*)(wp + 4096 +         kc * 32);
                    half8 wZ0 = *(const half8*)(wp + 32768 +        kc * 32);
                    half8 wZ1 = *(const half8*)(wp + 32768 + 4096 + kc * 32);
#pragma unroll
                    for (int n = 0; n < 2; ++n) {
                        const int cb = ((kc & 3) * 2 + n) * 512 + lo8;
                        half8 hh, hl;
                        if (kc < 4) {
                            hh = *(const half8*)&h0hi[prv][cb];
                            hl = *(const half8*)&h0lo[prv][cb];
                        } else {
                            hh = *(const half8*)&h1hi[cur][cb];
                            hl = *(const half8*)&h1lo[cur][cb];
                        }
                        aR[0][n] = MFMA(wR0, hh, aR[0][n]);
                        aR[0][n] = MFMA(wR0, hl, aR[0][n]);
                        aR[1][n] = MFMA(wR1, hh, aR[1][n]);
                        aR[1][n] = MFMA(wR1, hl, aR[1][n]);
                        aZ[0][n] = MFMA(wZ0, hh, aZ[0][n]);
                        aZ[0][n] = MFMA(wZ0, hl, aZ[0][n]);
                        aZ[1][n] = MFMA(wZ1, hh, aZ[1][n]);
                        aZ[1][n] = MFMA(wZ1, hl, aZ[1][n]);
                    }
                }

                // ---- pass B: N gate (split input/hidden halves) ----
                f32x4 aNi[2][2], aNh[2][2];            // [rb][n]
#pragma unroll
                for (int rb = 0; rb < 2; ++rb)
#pragma unroll
                    for (int n = 0; n < 2; ++n) {
                        aNi[rb][n] = (f32x4){0,0,0,0};
                        aNh[rb][n] = (f32x4){0,0,0,0};
                    }
#pragma unroll
                for (int kc = 0; kc < 8; ++kc) {
                    half8 wN0 = *(const half8*)(wp + 65536 +        kc * 32);
                    half8 wN1 = *(const half8*)(wp + 65536 + 4096 + kc * 32);
#pragma unroll
                    for (int n = 0; n < 2; ++n) {
                        const int cb = ((kc & 3) * 2 + n) * 512 + lo8;
                        half8 hh, hl;
                        if (kc < 4) {
                            hh = *(const half8*)&h0hi[prv][cb];
                            hl = *(const half8*)&h0lo[prv][cb];
                            aNi[0][n] = MFMA(wN0, hh, aNi[0][n]);
                            aNi[0][n] = MFMA(wN0, hl, aNi[0][n]);
                            aNi[1][n] = MFMA(wN1, hh, aNi[1][n]);
                            aNi[1][n] = MFMA(wN1, hl, aNi[1][n]);
                        } else {
                            hh = *(const half8*)&h1hi[cur][cb];
                            hl = *(const half8*)&h1lo[cur][cb];
                            aNh[0][n] = MFMA(wN0, hh, aNh[0][n]);
                            aNh[0][n] = MFMA(wN0, hl, aNh[0][n]);
                            aNh[1][n] = MFMA(wN1, hh, aNh[1][n]);
                            aNh[1][n] = MFMA(wN1, hl, aNh[1][n]);
                        }
                    }
                }

#pragma unroll
                for (int n = 0; n < 2; ++n)
#pragma unroll
                    for (int rb = 0; rb < 2; ++rb) {
                        const int ep = epb + rb * 256 + n * 512;
                        half4 hph = *(const half4*)&h1hi[cur][ep];
                        half4 hpl = *(const half4*)&h1lo[cur][ep];
                        half4 nh, nl;
#pragma unroll
                        for (int r = 0; r < 4; ++r) {
                            float rr = sigmoid_f(aR[rb][n][r]);
                            float zz = sigmoid_f(aZ[rb][n][r]);
                            float nn = tanh_f(aNi[rb][n][r] + rr * aNh[rb][n][r]);
                            float hprev = (float)hph[r] + (float)hpl[r];
                            float hn = (1.0f - zz) * nn + zz * hprev;
                            _Float16 hi = (_Float16)hn;
                            nh[r] = hi;
                            nl[r] = (_Float16)(hn - (float)hi);
                        }
                        *(half4*)&h1hi[prv][ep] = nh;
                        *(half4*)&h1lo[prv][ep] = nl;
                    }
            }
            __syncthreads();
        }
    }
}

extern "C" void kernel_launch(void* const* d_in, const int* in_sizes, int n_in,
                              void* d_out, int out_size, void* d_ws, size_t ws_size,
                              hipStream_t stream) {
    const int*   x     = (const int*)  d_in[0];
    const float* w_ih0 = (const float*)d_in[1];
    const float* w_hh0 = (const float*)d_in[2];
    const float* w_ih1 = (const float*)d_in[3];
    const float* w_hh1 = (const float*)d_in[4];
    const float* w_lin = (const float*)d_in[5];
    const float* b_lin = (const float*)d_in[6];
    float* out = (float*)d_out;
    _Float16* wsp = (_Float16*)d_ws;

    const int nbatch = in_sizes[0] / 64;

    prep_kernel<<<384, 256, 0, stream>>>(w_hh0, w_ih1, w_hh1, wsp);

    const int blocks = (nbatch + 31) / 32;
    rnn_wf_pipe<<<blocks, 512, 0, stream>>>(x, w_ih0, w_lin, b_lin, wsp, out, nbatch);
}

// Round 3
// 4425.628 us; speedup vs baseline: 1.3603x; 1.3603x over previous
//
#include <hip/hip_runtime.h>
#include <math.h>

#define PI_F 3.14159265358979323846f

typedef _Float16 half8 __attribute__((ext_vector_type(8)));
typedef _Float16 half4 __attribute__((ext_vector_type(4)));
typedef float f32x4 __attribute__((ext_vector_type(4)));

#define MFMA(a, b, c) __builtin_amdgcn_mfma_f32_16x16x32_f16(a, b, c, 0, 0, 0)
#define OFF_CAT 49152   // halfs: wcat starts after whh0 (3*128*128)

__device__ __forceinline__ float rcp_fast(float x) { return __builtin_amdgcn_rcpf(x); }
__device__ __forceinline__ float sigmoid_f(float x) {
    float e = __expf(-x);
    return rcp_fast(1.0f + e);
}
__device__ __forceinline__ float tanh_f(float x) {
    float ax = fabsf(x);
    float e  = __expf(-2.0f * ax);
    float t  = (1.0f - e) * rcp_fast(1.0f + e);
    return x >= 0.0f ? t : -t;
}

// Prep: f16 weights; concat [w_ih1|w_hh1] along K for layer 1.
__global__ void prep_kernel(const float* __restrict__ whh0,
                            const float* __restrict__ wih1,
                            const float* __restrict__ whh1,
                            _Float16* __restrict__ wsp) {
    int i = blockIdx.x * 256 + threadIdx.x;
    if (i < 49152) wsp[i] = (_Float16)whh0[i];
    if (i < 98304) {
        int n = i >> 8, k = i & 255;
        float v = (k < 128) ? wih1[(n << 7) + k] : whh1[(n << 7) + k - 128];
        wsp[OFF_CAT + i] = (_Float16)v;
    }
}

// 1024-thread blocks, 64 elems each, 1 block/CU (proven spill-free regime).
// Per tick, TWO balanced phases over ALL 16 waves (one barrier between; epoch
// analysis shows one barrier/tick suffices, so waves drift from B(t) into
// A(t+1) and smooth the MFMA pipe):
//   Phase A: h0(t) = GRU0(onehot(bit(t-1)), h0(t-1)).  wave w owns dim-block
//            db=w&7 (16 dims), elem-pair ep=w>>3 (2 of 4 elem-blocks); 3 gates
//            x 2 eb x (4kc x 2hl) = 48 MFMA/wave, 24 acc regs.
//   Phase B: h1(t) = GRU1(h0(t), h1(t-1)); same ownership, K=256 concat:
//            96 MFMA/wave, 32 acc regs.  Head (waves 0-3) for step t-1 reads
//            h1[prv] here.
// Epoch {B(t), head(t-1), A(t+1)}: B writes h1[t&1]; head reads h1[(t-1)&1];
// A(t+1) reads h0[t&1], writes h0[(t+1)&1] -> disjoint. Barrier separates
// A(t) (writes h0[t&1]) from B(t) (reads it).
//
// h planes (64 elems) in MFMA-B-frag chunk order, double-buffered by parity:
//   plane[buf][(kc*4 + eb)*512 + (qd*16 + l4)*8 + j] = h[e=eb*16+l4][dim=32kc+8qd+j]
//
// Weights are streamed from global (L2-hot) every phase, never register-
// resident (16 waves/CU -> 128 unified regs/wave; round-0 lesson). Phase acc
// sets retire into the epilogue WITHIN the phase -- no cross-phase acc
// liveness (round-2's 8.6GB-spill lesson). `wz` defeats LICM.

__global__ void __launch_bounds__(1024, 1) rnn_wf_pipe(
    const int*   __restrict__ x,
    const float* __restrict__ w_ih0,
    const float* __restrict__ w_lin,
    const float* __restrict__ b_lin,
    const _Float16* __restrict__ wsp,
    float*       __restrict__ out,
    int nbatch)
{
    __shared__ _Float16 h0hi[2][8192], h0lo[2][8192];
    __shared__ _Float16 h1hi[2][8192], h1lo[2][8192];
    __shared__ float gi0T[2][3][128];          // [prev-bit][gate][dim]
    __shared__ float wlinT[256];               // w_lin flat
    __shared__ unsigned long long bmk[64];     // per-element bit mask

    const int t    = threadIdx.x;
    const int wv   = t >> 6;                   // 0..15
    const int l4   = t & 15;
    const int q    = (t >> 4) & 3;
    const int db   = wv & 7;                   // dim-block (16 dims)
    const int e0   = (wv >> 3) << 1;           // first elem-block (0 or 2)
    const int ebg  = blockIdx.x * 64;

    // ---- init LDS ----
    for (int i = t; i < 8192; i += 1024) {     // 8192 ints = 2 bufs x 8192 halfs per array
        ((int*)h0hi)[i] = 0; ((int*)h0lo)[i] = 0;
        ((int*)h1hi)[i] = 0; ((int*)h1lo)[i] = 0;
    }
    if (t < 768) {
        int b = t / 384, rem = t - b * 384;
        ((float*)gi0T)[b * 384 + rem] = w_ih0[rem * 2 + b];
    }
    if (t < 256) wlinT[t] = w_lin[t];
    if (t < 256) {   // bit masks: thread t -> element t>>2, quarter t&3
        int el = t >> 2, qq = t & 3;
        int eg = ebg + el; if (eg >= nbatch) eg = nbatch - 1;
        const int* xr = x + (size_t)eg * 64 + qq * 16;
        unsigned long long m = 0ull;
#pragma unroll
        for (int i = 0; i < 16; ++i)
            m |= ((unsigned long long)((unsigned)(xr[i] + 1) >> 1)) << (qq * 16 + i);
        m |= __shfl_xor(m, 1);
        m |= __shfl_xor(m, 2);
        if (qq == 0) bmk[el] = m;
    }

    const int lo8 = ((q << 4) + l4) << 3;      // B-frag lane chunk offset (halfs)
    const int d0  = db * 16 + 4 * q;           // first of 4 dims this lane updates
    const int epb = (d0 >> 5) * 2048 + ((d0 >> 3) & 3) * 128 + l4 * 8 + (d0 & 7);

    // per-lane weight bases (g=0, kc=0): A-frag row = db*16 + l4, k-offset 8q
    const _Float16* wbase0 = wsp + (size_t)(db * 16 + l4) * 128 + 8 * q;
    const _Float16* wbase1 = wsp + OFF_CAT + (size_t)(db * 16 + l4) * 256 + 8 * q;

    // head state (waves 0-3, q-replicated)
    float amp = 1.0f, phs = 0.0f, nu = 0.0f, nd = 0.0f;
    float bl0 = 0.0f, bl1 = 0.0f;
    const int eh = (wv << 4) + l4;
    if (wv < 4) { bl0 = b_lin[0]; bl1 = b_lin[1]; }

    __syncthreads();

    unsigned wz = 0;
    for (int tick = 0; tick <= 64; ++tick) {
        const int cur = tick & 1, prv = cur ^ 1;

        if (tick < 64) {
            // ---- Phase A: h0(tick) ----
            asm volatile("" : "+v"(wz));           // defeat LICM on weight loads
            const _Float16* wp = wbase0 + wz;

            f32x4 acc[3][2];                       // [gate][ebi]
#pragma unroll
            for (int g = 0; g < 3; ++g)
#pragma unroll
                for (int ebi = 0; ebi < 2; ++ebi)
                    acc[g][ebi] = (f32x4){0,0,0,0};
#pragma unroll
            for (int kc = 0; kc < 4; ++kc) {
                half8 wR = *(const half8*)(wp +         kc * 32);
                half8 wZ = *(const half8*)(wp + 16384 + kc * 32);
                half8 wN = *(const half8*)(wp + 32768 + kc * 32);
#pragma unroll
                for (int ebi = 0; ebi < 2; ++ebi) {
                    const int cb = (kc * 4 + e0 + ebi) * 512 + lo8;
                    half8 hh = *(const half8*)&h0hi[prv][cb];
                    half8 hl = *(const half8*)&h0lo[prv][cb];
                    acc[0][ebi] = MFMA(wR, hh, acc[0][ebi]);
                    acc[1][ebi] = MFMA(wZ, hh, acc[1][ebi]);
                    acc[2][ebi] = MFMA(wN, hh, acc[2][ebi]);
                    acc[0][ebi] = MFMA(wR, hl, acc[0][ebi]);
                    acc[1][ebi] = MFMA(wZ, hl, acc[1][ebi]);
                    acc[2][ebi] = MFMA(wN, hl, acc[2][ebi]);
                }
            }
#pragma unroll
            for (int ebi = 0; ebi < 2; ++ebi) {
                const int ebx = e0 + ebi;
                const int e = ebx * 16 + l4;
                f32x4 giR = {0,0,0,0}, giZ = {0,0,0,0}, giN = {0,0,0,0};
                if (tick > 0) {
                    int pb = (int)((bmk[e] >> (tick - 1)) & 1ull);
                    const float* gp = &gi0T[pb][0][0];
                    giR = *(const f32x4*)(gp + d0);
                    giZ = *(const f32x4*)(gp + 128 + d0);
                    giN = *(const f32x4*)(gp + 256 + d0);
                }
                const int ep_ = epb + ebx * 512;
                half4 hph = *(const half4*)&h0hi[prv][ep_];
                half4 hpl = *(const half4*)&h0lo[prv][ep_];
                half4 nh, nl;
#pragma unroll
                for (int r = 0; r < 4; ++r) {
                    float rr = sigmoid_f(giR[r] + acc[0][ebi][r]);
                    float zz = sigmoid_f(giZ[r] + acc[1][ebi][r]);
                    float nn = tanh_f(giN[r] + rr * acc[2][ebi][r]);
                    float hprev = (float)hph[r] + (float)hpl[r];
                    float hn = (1.0f - zz) * nn + zz * hprev;
                    _Float16 hi = (_Float16)hn;
                    nh[r] = hi;
                    nl[r] = (_Float16)(hn - (float)hi);
                }
                *(half4*)&h0hi[cur][ep_] = nh;
                *(half4*)&h0lo[cur][ep_] = nl;
            }
        }

        __syncthreads();

        if (tick < 64) {
            // ---- Phase B: h1(tick) = GRU1(h0(tick), h1(tick-1)) ----
            asm volatile("" : "+v"(wz));           // defeat LICM on weight loads
            const _Float16* wp = wbase1 + wz;

            f32x4 aR[2], aZ[2], aNi[2], aNh[2];    // [ebi]
#pragma unroll
            for (int ebi = 0; ebi < 2; ++ebi) {
                aR[ebi]  = (f32x4){0,0,0,0};
                aZ[ebi]  = (f32x4){0,0,0,0};
                aNi[ebi] = (f32x4){0,0,0,0};
                aNh[ebi] = (f32x4){0,0,0,0};
            }
#pragma unroll
            for (int kc = 0; kc < 8; ++kc) {
                half8 wR = *(const half8*)(wp +         kc * 32);
                half8 wZ = *(const half8*)(wp + 32768 + kc * 32);
                half8 wN = *(const half8*)(wp + 65536 + kc * 32);
#pragma unroll
                for (int ebi = 0; ebi < 2; ++ebi) {
                    const int cb = ((kc & 3) * 4 + e0 + ebi) * 512 + lo8;
                    half8 hh, hl;
                    if (kc < 4) {
                        hh = *(const half8*)&h0hi[cur][cb];
                        hl = *(const half8*)&h0lo[cur][cb];
                    } else {
                        hh = *(const half8*)&h1hi[prv][cb];
                        hl = *(const half8*)&h1lo[prv][cb];
                    }
                    aR[ebi] = MFMA(wR, hh, aR[ebi]);
                    aR[ebi] = MFMA(wR, hl, aR[ebi]);
                    aZ[ebi] = MFMA(wZ, hh, aZ[ebi]);
                    aZ[ebi] = MFMA(wZ, hl, aZ[ebi]);
                    if (kc < 4) {
                        aNi[ebi] = MFMA(wN, hh, aNi[ebi]);
                        aNi[ebi] = MFMA(wN, hl, aNi[ebi]);
                    } else {
                        aNh[ebi] = MFMA(wN, hh, aNh[ebi]);
                        aNh[ebi] = MFMA(wN, hl, aNh[ebi]);
                    }
                }
            }
#pragma unroll
            for (int ebi = 0; ebi < 2; ++ebi) {
                const int ep_ = epb + (e0 + ebi) * 512;
                half4 hph = *(const half4*)&h1hi[prv][ep_];
                half4 hpl = *(const half4*)&h1lo[prv][ep_];
                half4 nh, nl;
#pragma unroll
                for (int r = 0; r < 4; ++r) {
                    float rr = sigmoid_f(aR[ebi][r]);
                    float zz = sigmoid_f(aZ[ebi][r]);
                    float nn = tanh_f(aNi[ebi][r] + rr * aNh[ebi][r]);
                    float hprev = (float)hph[r] + (float)hpl[r];
                    float hn = (1.0f - zz) * nn + zz * hprev;
                    _Float16 hi = (_Float16)hn;
                    nh[r] = hi;
                    nl[r] = (_Float16)(hn - (float)hi);
                }
                *(half4*)&h1hi[cur][ep_] = nh;
                *(half4*)&h1lo[cur][ep_] = nl;
            }
        }

        if (wv < 4 && tick >= 1) {
            // head for step s = tick-1; h1(s) lives in buf s&1 == prv
            const int s = tick - 1;
            float l0 = 0.0f, l1 = 0.0f;
#pragma unroll
            for (int qq = 0; qq < 4; ++qq) {   // this q-copy handles kc = q
                const int cb = (q * 4 + wv) * 512 + (qq * 16 + l4) * 8;
                half8 hh = *(const half8*)&h1hi[prv][cb];
                half8 hl = *(const half8*)&h1lo[prv][cb];
                const float* wpl = &wlinT[32 * q + 8 * qq];
#pragma unroll
                for (int j = 0; j < 8; ++j) {
                    float hv = (float)hh[j] + (float)hl[j];
                    l0 = fmaf(hv, wpl[j], l0);
                    l1 = fmaf(hv, wpl[128 + j], l1);
                }
            }
            l0 += __shfl_xor(l0, 16); l0 += __shfl_xor(l0, 32); l0 += bl0;
            l1 += __shfl_xor(l1, 16); l1 += __shfl_xor(l1, 32); l1 += bl1;

            float p0 = sigmoid_f(l0 - l1);
            float p1 = sigmoid_f(l1 - l0);
            float y0 = sqrtf(p0), y1 = sqrtf(p1);
            float ph0 = PI_F * l0 * rcp_fast(1.0f + fabsf(l0));
            float ph1 = PI_F * l1 * rcp_fast(1.0f + fabsf(l1));

            int bit = (int)((bmk[eh] >> s) & 1ull);
            bool is_even = (s & 1) == 0;
            float num   = is_even ? nu : nd;
            float lower = -16.0f + (float)(s >> 1);
            float occ   = (num < 16.0f) ? 1.0f : 0.0f;
            float unocc = (num > lower) ? 1.0f : 0.0f;
            if (s >= 16) {
                float m0 = y0 * unocc, m1 = y1 * occ;
                float nrm = fmaxf(sqrtf(m0 * m0 + m1 * m1), 1e-12f);
                float rn  = rcp_fast(nrm);
                y0 = m0 * rn; y1 = m1 * rn;
            }
            if (is_even) nu += (float)bit; else nd += (float)bit;
            amp *= bit ? y1 : y0;
            phs += bit ? ph1 : ph0;
        }
    }

    if (wv < 4 && q == 0) {
        int eg = ebg + eh;
        if (eg < nbatch) {
            float s, c;
            sincosf(phs, &s, &c);
            out[eg]          = amp * c;
            out[nbatch + eg] = amp * s;
        }
    }
}

extern "C" void kernel_launch(void* const* d_in, const int* in_sizes, int n_in,
                              void* d_out, int out_size, void* d_ws, size_t ws_size,
                              hipStream_t stream) {
    const int*   x     = (const int*)  d_in[0];
    const float* w_ih0 = (const float*)d_in[1];
    const float* w_hh0 = (const float*)d_in[2];
    const float* w_ih1 = (const float*)d_in[3];
    const float* w_hh1 = (const float*)d_in[4];
    const float* w_lin = (const float*)d_in[5];
    const float* b_lin = (const float*)d_in[6];
    float* out = (float*)d_out;
    _Float16* wsp = (_Float16*)d_ws;

    const int nbatch = in_sizes[0] / 64;

    prep_kernel<<<384, 256, 0, stream>>>(w_hh0, w_ih1, w_hh1, wsp);

    const int blocks = (nbatch + 63) / 64;
    rnn_wf_pipe<<<blocks, 1024, 0, stream>>>(x, w_ih0, w_lin, b_lin, wsp, out, nbatch);
}

// Round 4
// 2317.837 us; speedup vs baseline: 2.5973x; 1.9094x over previous
//
#include <hip/hip_runtime.h>
#include <math.h>

#define PI_F 3.14159265358979323846f

typedef _Float16 half8 __attribute__((ext_vector_type(8)));
typedef _Float16 half4 __attribute__((ext_vector_type(4)));
typedef float f32x4 __attribute__((ext_vector_type(4)));

#define MFMA(a, b, c) __builtin_amdgcn_mfma_f32_16x16x32_f16(a, b, c, 0, 0, 0)
#define OFF_CAT 49152   // halfs: wcat starts after whh0 (3*128*128)

__device__ __forceinline__ float rcp_fast(float x) { return __builtin_amdgcn_rcpf(x); }
__device__ __forceinline__ float sigmoid_f(float x) {
    float e = __expf(-x);
    return rcp_fast(1.0f + e);
}
__device__ __forceinline__ float tanh_f(float x) {
    float ax = fabsf(x);
    float e  = __expf(-2.0f * ax);
    float t  = (1.0f - e) * rcp_fast(1.0f + e);
    return x >= 0.0f ? t : -t;
}

// Prep: f16 weights; concat [w_ih1|w_hh1] along K for layer 1.
__global__ void prep_kernel(const float* __restrict__ whh0,
                            const float* __restrict__ wih1,
                            const float* __restrict__ whh1,
                            _Float16* __restrict__ wsp) {
    int i = blockIdx.x * 256 + threadIdx.x;
    if (i < 49152) wsp[i] = (_Float16)whh0[i];
    if (i < 98304) {
        int n = i >> 8, k = i & 255;
        float v = (k < 128) ? wih1[(n << 7) + k] : whh1[(n << 7) + k - 128];
        wsp[OFF_CAT + i] = (_Float16)v;
    }
}

// 512-thread blocks (8 waves), 64 elems each, LDS 135.7 KB -> 1 block/CU ->
// 2 waves/SIMD -> 256 unified regs/wave. Each wave owns dim-block wv (16 dims)
// for BOTH layers and keeps its full weight slices REGISTER-RESIDENT:
// W0 = 12 half8 (48 VGPR) + W1 = 24 half8 (96 VGPR), loaded once before the
// tick loop. This removes the ~300 KB/tick/CU of L2 weight re-streaming that
// dominated rounds 1-3 (rounds 0/2 showed the 16-wave/128-reg regime spills
// if weights are resident; 8 waves/256 regs is the only spill-free resident
// regime). Per-eb accumulators (<=16 VGPR) retire within their iteration:
// peak live ~210 regs.
//
// h planes (64 elems) in MFMA-B-frag chunk order, double-buffered by parity:
//   plane[buf][(kc*4 + eb)*512 + (qd*16 + l4)*8 + j] = h[e=eb*16+l4][dim=32kc+8qd+j]
// Tick t: A: h0(t)=GRU0(onehot(bit(t-1)), h0(t-1)) reads h0[prv] writes h0[cur]
//         | bar | B: h1(t)=GRU1(h0(t), h1(t-1)) reads h0[cur],h1[prv] writes
//         h1[cur] | bar | head(t) (waves 0-3, reads h1[cur]) overlapping
//         A(t+1) on waves 4-7.  Per-acc MFMA order identical to the verified
//         round-1 kernel (kc ascending, hh before hl) -> bit-identical output.

__global__ void __launch_bounds__(512, 2) rnn_wf_pipe(
    const int*   __restrict__ x,
    const float* __restrict__ w_ih0,
    const float* __restrict__ w_lin,
    const float* __restrict__ b_lin,
    const _Float16* __restrict__ wsp,
    float*       __restrict__ out,
    int nbatch)
{
    __shared__ _Float16 h0hi[2][8192], h0lo[2][8192];
    __shared__ _Float16 h1hi[2][8192], h1lo[2][8192];
    __shared__ float gi0T[2][3][128];          // [prev-bit][gate][dim]
    __shared__ float wlinT[256];               // w_lin flat
    __shared__ unsigned long long bmk[64];     // per-element bit mask

    const int t    = threadIdx.x;
    const int wv   = t >> 6;                   // 0..7 = dim-block (16 dims)
    const int l4   = t & 15;
    const int q    = (t >> 4) & 3;
    const int ebg  = blockIdx.x * 64;

    // ---- init LDS ----
    for (int i = t; i < 8192; i += 512) {      // 8192 ints = 2 bufs x 8192 halfs per array
        ((int*)h0hi)[i] = 0; ((int*)h0lo)[i] = 0;
        ((int*)h1hi)[i] = 0; ((int*)h1lo)[i] = 0;
    }
    for (int i = t; i < 768; i += 512) {
        int b = i / 384, rem = i - b * 384;
        ((float*)gi0T)[b * 384 + rem] = w_ih0[rem * 2 + b];
    }
    if (t < 256) wlinT[t] = w_lin[t];
    if (t < 256) {   // bit masks: thread t -> element t>>2, quarter t&3
        int el = t >> 2, qq = t & 3;
        int eg = ebg + el; if (eg >= nbatch) eg = nbatch - 1;
        const int* xr = x + (size_t)eg * 64 + qq * 16;
        unsigned long long m = 0ull;
#pragma unroll
        for (int i = 0; i < 16; ++i)
            m |= ((unsigned long long)((unsigned)(xr[i] + 1) >> 1)) << (qq * 16 + i);
        m |= __shfl_xor(m, 1);
        m |= __shfl_xor(m, 2);
        if (qq == 0) bmk[el] = m;
    }

    const int lo8 = ((q << 4) + l4) << 3;      // B-frag lane chunk offset (halfs)
    const int d0  = wv * 16 + 4 * q;           // first of 4 dims this lane updates
    const int epb = (d0 >> 5) * 2048 + ((d0 >> 3) & 3) * 128 + l4 * 8 + (d0 & 7);

    // ---- register-resident weights ----
    half8 w0[3][4];                            // 48 VGPR
#pragma unroll
    for (int g = 0; g < 3; ++g)
#pragma unroll
        for (int kc = 0; kc < 4; ++kc)
            w0[g][kc] = *(const half8*)(wsp + (size_t)(g * 128 + 16 * wv + l4) * 128 + 32 * kc + 8 * q);
    half8 w1[3][8];                            // 96 VGPR
#pragma unroll
    for (int g = 0; g < 3; ++g)
#pragma unroll
        for (int kc = 0; kc < 8; ++kc)
            w1[g][kc] = *(const half8*)(wsp + OFF_CAT + (size_t)(g * 128 + 16 * wv + l4) * 256 + 32 * kc + 8 * q);

    // head state (waves 0-3, q-replicated)
    float amp = 1.0f, phs = 0.0f, nu = 0.0f, nd = 0.0f;
    float bl0 = 0.0f, bl1 = 0.0f;
    const int eh = (wv << 4) + l4;
    if (wv < 4) { bl0 = b_lin[0]; bl1 = b_lin[1]; }

    __syncthreads();

    for (int tick = 0; tick < 64; ++tick) {
        const int cur = tick & 1, prv = cur ^ 1;

        // ---- Phase A: h0(tick) ----
#pragma unroll
        for (int eb = 0; eb < 4; ++eb) {
            f32x4 aR = {0,0,0,0}, aZ = {0,0,0,0}, aN = {0,0,0,0};
#pragma unroll
            for (int kc = 0; kc < 4; ++kc) {
                const int cb = (kc * 4 + eb) * 512 + lo8;
                half8 hh = *(const half8*)&h0hi[prv][cb];
                half8 hl = *(const half8*)&h0lo[prv][cb];
                aR = MFMA(w0[0][kc], hh, aR);
                aZ = MFMA(w0[1][kc], hh, aZ);
                aN = MFMA(w0[2][kc], hh, aN);
                aR = MFMA(w0[0][kc], hl, aR);
                aZ = MFMA(w0[1][kc], hl, aZ);
                aN = MFMA(w0[2][kc], hl, aN);
            }
            const int e = eb * 16 + l4;
            f32x4 giR = {0,0,0,0}, giZ = {0,0,0,0}, giN = {0,0,0,0};
            if (tick > 0) {
                int pb = (int)((bmk[e] >> (tick - 1)) & 1ull);
                const float* gp = &gi0T[pb][0][0];
                giR = *(const f32x4*)(gp + d0);
                giZ = *(const f32x4*)(gp + 128 + d0);
                giN = *(const f32x4*)(gp + 256 + d0);
            }
            const int ep_ = epb + eb * 512;
            half4 hph = *(const half4*)&h0hi[prv][ep_];
            half4 hpl = *(const half4*)&h0lo[prv][ep_];
            half4 nh, nl;
#pragma unroll
            for (int r = 0; r < 4; ++r) {
                float rr = sigmoid_f(giR[r] + aR[r]);
                float zz = sigmoid_f(giZ[r] + aZ[r]);
                float nn = tanh_f(giN[r] + rr * aN[r]);
                float hprev = (float)hph[r] + (float)hpl[r];
                float hn = (1.0f - zz) * nn + zz * hprev;
                _Float16 hi = (_Float16)hn;
                nh[r] = hi;
                nl[r] = (_Float16)(hn - (float)hi);
            }
            *(half4*)&h0hi[cur][ep_] = nh;
            *(half4*)&h0lo[cur][ep_] = nl;
        }

        __syncthreads();

        // ---- Phase B: h1(tick) = GRU1(h0(tick), h1(tick-1)) ----
#pragma unroll
        for (int eb = 0; eb < 4; ++eb) {
            f32x4 aR = {0,0,0,0}, aZ = {0,0,0,0};
            f32x4 aNi = {0,0,0,0}, aNh = {0,0,0,0};
#pragma unroll
            for (int kc = 0; kc < 8; ++kc) {
                const int cb = ((kc & 3) * 4 + eb) * 512 + lo8;
                half8 hh, hl;
                if (kc < 4) {
                    hh = *(const half8*)&h0hi[cur][cb];
                    hl = *(const half8*)&h0lo[cur][cb];
                } else {
                    hh = *(const half8*)&h1hi[prv][cb];
                    hl = *(const half8*)&h1lo[prv][cb];
                }
                aR = MFMA(w1[0][kc], hh, aR);
                aR = MFMA(w1[0][kc], hl, aR);
                aZ = MFMA(w1[1][kc], hh, aZ);
                aZ = MFMA(w1[1][kc], hl, aZ);
                if (kc < 4) {
                    aNi = MFMA(w1[2][kc], hh, aNi);
                    aNi = MFMA(w1[2][kc], hl, aNi);
                } else {
                    aNh = MFMA(w1[2][kc], hh, aNh);
                    aNh = MFMA(w1[2][kc], hl, aNh);
                }
            }
            const int ep_ = epb + eb * 512;
            half4 hph = *(const half4*)&h1hi[prv][ep_];
            half4 hpl = *(const half4*)&h1lo[prv][ep_];
            half4 nh, nl;
#pragma unroll
            for (int r = 0; r < 4; ++r) {
                float rr = sigmoid_f(aR[r]);
                float zz = sigmoid_f(aZ[r]);
                float nn = tanh_f(aNi[r] + rr * aNh[r]);
                float hprev = (float)hph[r] + (float)hpl[r];
                float hn = (1.0f - zz) * nn + zz * hprev;
                _Float16 hi = (_Float16)hn;
                nh[r] = hi;
                nl[r] = (_Float16)(hn - (float)hi);
            }
            *(half4*)&h1hi[cur][ep_] = nh;
            *(half4*)&h1lo[cur][ep_] = nl;
        }

        __syncthreads();

        // ---- head for step s = tick; h1(s) in buf cur.  Waves 0-3 only;
        //      waves 4-7 proceed straight into A(tick+1). ----
        if (wv < 4) {
            const int s = tick;
            float l0 = 0.0f, l1 = 0.0f;
#pragma unroll
            for (int qq = 0; qq < 4; ++qq) {   // this q-copy handles kc = q
                const int cb = (q * 4 + wv) * 512 + (qq * 16 + l4) * 8;
                half8 hh = *(const half8*)&h1hi[cur][cb];
                half8 hl = *(const half8*)&h1lo[cur][cb];
                const float* wpl = &wlinT[32 * q + 8 * qq];
#pragma unroll
                for (int j = 0; j < 8; ++j) {
                    float hv = (float)hh[j] + (float)hl[j];
                    l0 = fmaf(hv, wpl[j], l0);
                    l1 = fmaf(hv, wpl[128 + j], l1);
                }
            }
            l0 += __shfl_xor(l0, 16); l0 += __shfl_xor(l0, 32); l0 += bl0;
            l1 += __shfl_xor(l1, 16); l1 += __shfl_xor(l1, 32); l1 += bl1;

            float p0 = sigmoid_f(l0 - l1);
            float p1 = sigmoid_f(l1 - l0);
            float y0 = sqrtf(p0), y1 = sqrtf(p1);
            float ph0 = PI_F * l0 * rcp_fast(1.0f + fabsf(l0));
            float ph1 = PI_F * l1 * rcp_fast(1.0f + fabsf(l1));

            int bit = (int)((bmk[eh] >> s) & 1ull);
            bool is_even = (s & 1) == 0;
            float num   = is_even ? nu : nd;
            float lower = -16.0f + (float)(s >> 1);
            float occ   = (num < 16.0f) ? 1.0f : 0.0f;
            float unocc = (num > lower) ? 1.0f : 0.0f;
            if (s >= 16) {
                float m0 = y0 * unocc, m1 = y1 * occ;
                float nrm = fmaxf(sqrtf(m0 * m0 + m1 * m1), 1e-12f);
                float rn  = rcp_fast(nrm);
                y0 = m0 * rn; y1 = m1 * rn;
            }
            if (is_even) nu += (float)bit; else nd += (float)bit;
            amp *= bit ? y1 : y0;
            phs += bit ? ph1 : ph0;
        }
    }

    if (wv < 4 && q == 0) {
        int eg = ebg + eh;
        if (eg < nbatch) {
            float s, c;
            sincosf(phs, &s, &c);
            out[eg]          = amp * c;
            out[nbatch + eg] = amp * s;
        }
    }
}

extern "C" void kernel_launch(void* const* d_in, const int* in_sizes, int n_in,
                              void* d_out, int out_size, void* d_ws, size_t ws_size,
                              hipStream_t stream) {
    const int*   x     = (const int*)  d_in[0];
    const float* w_ih0 = (const float*)d_in[1];
    const float* w_hh0 = (const float*)d_in[2];
    const float* w_ih1 = (const float*)d_in[3];
    const float* w_hh1 = (const float*)d_in[4];
    const float* w_lin = (const float*)d_in[5];
    const float* b_lin = (const float*)d_in[6];
    float* out = (float*)d_out;
    _Float16* wsp = (_Float16*)d_ws;

    const int nbatch = in_sizes[0] / 64;

    prep_kernel<<<384, 256, 0, stream>>>(w_hh0, w_ih1, w_hh1, wsp);

    const int blocks = (nbatch + 63) / 64;
    rnn_wf_pipe<<<blocks, 512, 0, stream>>>(x, w_ih0, w_lin, b_lin, wsp, out, nbatch);
}

// Round 5
// 2269.291 us; speedup vs baseline: 2.6529x; 1.0214x over previous
//
#include <hip/hip_runtime.h>
#include <math.h>

#define PI_F 3.14159265358979323846f

typedef _Float16 half8 __attribute__((ext_vector_type(8)));
typedef _Float16 half4 __attribute__((ext_vector_type(4)));
typedef float f32x4 __attribute__((ext_vector_type(4)));

#define MFMA(a, b, c) __builtin_amdgcn_mfma_f32_16x16x32_f16(a, b, c, 0, 0, 0)
#define OFF_CAT 49152   // halfs: wcat starts after whh0 (3*128*128)

__device__ __forceinline__ float rcp_fast(float x) { return __builtin_amdgcn_rcpf(x); }
__device__ __forceinline__ float sigmoid_f(float x) {
    float e = __expf(-x);
    return rcp_fast(1.0f + e);
}
__device__ __forceinline__ float tanh_f(float x) {
    float ax = fabsf(x);
    float e  = __expf(-2.0f * ax);
    float t  = (1.0f - e) * rcp_fast(1.0f + e);
    return x >= 0.0f ? t : -t;
}

// Prep: f16 weights; concat [w_ih1|w_hh1] along K for layer 1.
__global__ void prep_kernel(const float* __restrict__ whh0,
                            const float* __restrict__ wih1,
                            const float* __restrict__ whh1,
                            _Float16* __restrict__ wsp) {
    int i = blockIdx.x * 256 + threadIdx.x;
    if (i < 49152) wsp[i] = (_Float16)whh0[i];
    if (i < 98304) {
        int n = i >> 8, k = i & 255;
        float v = (k < 128) ? wih1[(n << 7) + k] : whh1[(n << 7) + k - 128];
        wsp[OFF_CAT + i] = (_Float16)v;
    }
}

// 512-thread blocks (8 waves), 64 elems each, LDS 135.7 KB -> 1 block/CU ->
// 2 waves/SIMD -> 256 unified regs/wave. Each wave owns dim-block wv (16 dims)
// for BOTH layers and keeps its full weight slices REGISTER-RESIDENT:
// W0 = 12 half8 (48 VGPR) + W1 = 24 half8 (96 VGPR).
//
// Round-4 lesson: without pinning, the compiler allocated only 128 VGPR --
// i.e. it sank part of the weight set back to per-tick L2 reloads (invisible
// in FETCH_SIZE since L2 hits don't count). The asm "+v" pins at the top of
// the tick loop make each weight vector an opaque loop-carried register, so
// rematerialization from memory is illegal -> true residency.
//
// Round-4 bank-conflict forensics: head reads at (qq*16+l4)*8 within chunks
// (q*4+wv)*1024B (chunk base == 0 mod 128B) alias all 4 q-groups onto the
// same 16 bank-slots -> 8-way conflict (2.94x, ~1.5K cyc/tick). Fixed by
// lane-linear head reads (offset lane*16B, stride-1, conflict-free): lane
// (q,l4) now accumulates dims 32*ks+8*q+j over chunk loop ks; the xor-16/32
// reduce is unchanged.
//
// h planes (64 elems) in MFMA-B-frag chunk order, double-buffered by parity:
//   plane[buf][(kc*4 + eb)*512 + (qd*16 + l4)*8 + j] = h[e=eb*16+l4][dim=32kc+8qd+j]
// Tick t: A: h0(t)=GRU0(onehot(bit(t-1)), h0(t-1)) reads h0[prv] writes h0[cur]
//         | bar | B: h1(t)=GRU1(h0(t), h1(t-1)) reads h0[cur],h1[prv] writes
//         h1[cur] | bar | head(t) (waves 0-3, reads h1[cur]) overlapping
//         A(t+1) on waves 4-7.  Per-acc MFMA order identical to the verified
//         round-1/4 kernels -> GRU state bit-identical.

__global__ void __launch_bounds__(512, 2) rnn_wf_pipe(
    const int*   __restrict__ x,
    const float* __restrict__ w_ih0,
    const float* __restrict__ w_lin,
    const float* __restrict__ b_lin,
    const _Float16* __restrict__ wsp,
    float*       __restrict__ out,
    int nbatch)
{
    __shared__ _Float16 h0hi[2][8192], h0lo[2][8192];
    __shared__ _Float16 h1hi[2][8192], h1lo[2][8192];
    __shared__ float gi0T[2][3][128];          // [prev-bit][gate][dim]
    __shared__ float wlinT[256];               // w_lin flat
    __shared__ unsigned long long bmk[64];     // per-element bit mask

    const int t    = threadIdx.x;
    const int wv   = t >> 6;                   // 0..7 = dim-block (16 dims)
    const int l4   = t & 15;
    const int q    = (t >> 4) & 3;
    const int ebg  = blockIdx.x * 64;

    // ---- init LDS ----
    for (int i = t; i < 8192; i += 512) {      // 8192 ints = 2 bufs x 8192 halfs per array
        ((int*)h0hi)[i] = 0; ((int*)h0lo)[i] = 0;
        ((int*)h1hi)[i] = 0; ((int*)h1lo)[i] = 0;
    }
    for (int i = t; i < 768; i += 512) {
        int b = i / 384, rem = i - b * 384;
        ((float*)gi0T)[b * 384 + rem] = w_ih0[rem * 2 + b];
    }
    if (t < 256) wlinT[t] = w_lin[t];
    if (t < 256) {   // bit masks: thread t -> element t>>2, quarter t&3
        int el = t >> 2, qq = t & 3;
        int eg = ebg + el; if (eg >= nbatch) eg = nbatch - 1;
        const int* xr = x + (size_t)eg * 64 + qq * 16;
        unsigned long long m = 0ull;
#pragma unroll
        for (int i = 0; i < 16; ++i)
            m |= ((unsigned long long)((unsigned)(xr[i] + 1) >> 1)) << (qq * 16 + i);
        m |= __shfl_xor(m, 1);
        m |= __shfl_xor(m, 2);
        if (qq == 0) bmk[el] = m;
    }

    const int lo8 = ((q << 4) + l4) << 3;      // = lane*8 halfs: B-frag chunk offset
    const int d0  = wv * 16 + 4 * q;           // first of 4 dims this lane updates
    const int epb = (d0 >> 5) * 2048 + ((d0 >> 3) & 3) * 128 + l4 * 8 + (d0 & 7);

    // ---- register-resident weights ----
    half8 w0[3][4];                            // 48 VGPR
#pragma unroll
    for (int g = 0; g < 3; ++g)
#pragma unroll
        for (int kc = 0; kc < 4; ++kc)
            w0[g][kc] = *(const half8*)(wsp + (size_t)(g * 128 + 16 * wv + l4) * 128 + 32 * kc + 8 * q);
    half8 w1[3][8];                            // 96 VGPR
#pragma unroll
    for (int g = 0; g < 3; ++g)
#pragma unroll
        for (int kc = 0; kc < 8; ++kc)
            w1[g][kc] = *(const half8*)(wsp + OFF_CAT + (size_t)(g * 128 + 16 * wv + l4) * 256 + 32 * kc + 8 * q);

    // head state (waves 0-3, q-replicated)
    float amp = 1.0f, phs = 0.0f, nu = 0.0f, nd = 0.0f;
    float bl0 = 0.0f, bl1 = 0.0f;
    const int eh = (wv << 4) + l4;
    if (wv < 4) { bl0 = b_lin[0]; bl1 = b_lin[1]; }

    __syncthreads();

    for (int tick = 0; tick < 64; ++tick) {
        const int cur = tick & 1, prv = cur ^ 1;

        // ---- pin weights: opaque loop-carried registers; compiler cannot
        //      rematerialize them from global inside the loop ----
#pragma unroll
        for (int g = 0; g < 3; ++g) {
#pragma unroll
            for (int kc = 0; kc < 4; ++kc) asm volatile("" : "+v"(w0[g][kc]));
#pragma unroll
            for (int kc = 0; kc < 8; ++kc) asm volatile("" : "+v"(w1[g][kc]));
        }

        // ---- Phase A: h0(tick) ----
#pragma unroll
        for (int eb = 0; eb < 4; ++eb) {
            f32x4 aR = {0,0,0,0}, aZ = {0,0,0,0}, aN = {0,0,0,0};
#pragma unroll
            for (int kc = 0; kc < 4; ++kc) {
                const int cb = (kc * 4 + eb) * 512 + lo8;
                half8 hh = *(const half8*)&h0hi[prv][cb];
                half8 hl = *(const half8*)&h0lo[prv][cb];
                aR = MFMA(w0[0][kc], hh, aR);
                aZ = MFMA(w0[1][kc], hh, aZ);
                aN = MFMA(w0[2][kc], hh, aN);
                aR = MFMA(w0[0][kc], hl, aR);
                aZ = MFMA(w0[1][kc], hl, aZ);
                aN = MFMA(w0[2][kc], hl, aN);
            }
            const int e = eb * 16 + l4;
            f32x4 giR = {0,0,0,0}, giZ = {0,0,0,0}, giN = {0,0,0,0};
            if (tick > 0) {
                int pb = (int)((bmk[e] >> (tick - 1)) & 1ull);
                const float* gp = &gi0T[pb][0][0];
                giR = *(const f32x4*)(gp + d0);
                giZ = *(const f32x4*)(gp + 128 + d0);
                giN = *(const f32x4*)(gp + 256 + d0);
            }
            const int ep_ = epb + eb * 512;
            half4 hph = *(const half4*)&h0hi[prv][ep_];
            half4 hpl = *(const half4*)&h0lo[prv][ep_];
            half4 nh, nl;
#pragma unroll
            for (int r = 0; r < 4; ++r) {
                float rr = sigmoid_f(giR[r] + aR[r]);
                float zz = sigmoid_f(giZ[r] + aZ[r]);
                float nn = tanh_f(giN[r] + rr * aN[r]);
                float hprev = (float)hph[r] + (float)hpl[r];
                float hn = (1.0f - zz) * nn + zz * hprev;
                _Float16 hi = (_Float16)hn;
                nh[r] = hi;
                nl[r] = (_Float16)(hn - (float)hi);
            }
            *(half4*)&h0hi[cur][ep_] = nh;
            *(half4*)&h0lo[cur][ep_] = nl;
        }

        __syncthreads();

        // ---- Phase B: h1(tick) = GRU1(h0(tick), h1(tick-1)) ----
#pragma unroll
        for (int eb = 0; eb < 4; ++eb) {
            f32x4 aR = {0,0,0,0}, aZ = {0,0,0,0};
            f32x4 aNi = {0,0,0,0}, aNh = {0,0,0,0};
#pragma unroll
            for (int kc = 0; kc < 8; ++kc) {
                const int cb = ((kc & 3) * 4 + eb) * 512 + lo8;
                half8 hh, hl;
                if (kc < 4) {
                    hh = *(const half8*)&h0hi[cur][cb];
                    hl = *(const half8*)&h0lo[cur][cb];
                } else {
                    hh = *(const half8*)&h1hi[prv][cb];
                    hl = *(const half8*)&h1lo[prv][cb];
                }
                aR = MFMA(w1[0][kc], hh, aR);
                aR = MFMA(w1[0][kc], hl, aR);
                aZ = MFMA(w1[1][kc], hh, aZ);
                aZ = MFMA(w1[1][kc], hl, aZ);
                if (kc < 4) {
                    aNi = MFMA(w1[2][kc], hh, aNi);
                    aNi = MFMA(w1[2][kc], hl, aNi);
                } else {
                    aNh = MFMA(w1[2][kc], hh, aNh);
                    aNh = MFMA(w1[2][kc], hl, aNh);
                }
            }
            const int ep_ = epb + eb * 512;
            half4 hph = *(const half4*)&h1hi[prv][ep_];
            half4 hpl = *(const half4*)&h1lo[prv][ep_];
            half4 nh, nl;
#pragma unroll
            for (int r = 0; r < 4; ++r) {
                float rr = sigmoid_f(aR[r]);
                float zz = sigmoid_f(aZ[r]);
                float nn = tanh_f(aNi[r] + rr * aNh[r]);
                float hprev = (float)hph[r] + (float)hpl[r];
                float hn = (1.0f - zz) * nn + zz * hprev;
                _Float16 hi = (_Float16)hn;
                nh[r] = hi;
                nl[r] = (_Float16)(hn - (float)hi);
            }
            *(half4*)&h1hi[cur][ep_] = nh;
            *(half4*)&h1lo[cur][ep_] = nl;
        }

        __syncthreads();

        // ---- head for step s = tick; h1(s) in buf cur.  Waves 0-3 only;
        //      waves 4-7 proceed straight into A(tick+1).
        //      Lane-linear reads (offset lane*16B, stride-1, conflict-free):
        //      lane (q,l4) accumulates dims 32*ks+8*q+j of element wv*16+l4;
        //      the xor-16/32 reduce combines q-groups exactly as before. ----
        if (wv < 4) {
            const int s = tick;
            float l0 = 0.0f, l1 = 0.0f;
#pragma unroll
            for (int ks = 0; ks < 4; ++ks) {
                const int cb = (ks * 4 + wv) * 512 + lo8;
                half8 hh = *(const half8*)&h1hi[cur][cb];
                half8 hl = *(const half8*)&h1lo[cur][cb];
                const float* wpl = &wlinT[32 * ks + 8 * q];
#pragma unroll
                for (int j = 0; j < 8; ++j) {
                    float hv = (float)hh[j] + (float)hl[j];
                    l0 = fmaf(hv, wpl[j], l0);
                    l1 = fmaf(hv, wpl[128 + j], l1);
                }
            }
            l0 += __shfl_xor(l0, 16); l0 += __shfl_xor(l0, 32); l0 += bl0;
            l1 += __shfl_xor(l1, 16); l1 += __shfl_xor(l1, 32); l1 += bl1;

            float p0 = sigmoid_f(l0 - l1);
            float p1 = sigmoid_f(l1 - l0);
            float y0 = sqrtf(p0), y1 = sqrtf(p1);
            float ph0 = PI_F * l0 * rcp_fast(1.0f + fabsf(l0));
            float ph1 = PI_F * l1 * rcp_fast(1.0f + fabsf(l1));

            int bit = (int)((bmk[eh] >> s) & 1ull);
            bool is_even = (s & 1) == 0;
            float num   = is_even ? nu : nd;
            float lower = -16.0f + (float)(s >> 1);
            float occ   = (num < 16.0f) ? 1.0f : 0.0f;
            float unocc = (num > lower) ? 1.0f : 0.0f;
            if (s >= 16) {
                float m0 = y0 * unocc, m1 = y1 * occ;
                float nrm = fmaxf(sqrtf(m0 * m0 + m1 * m1), 1e-12f);
                float rn  = rcp_fast(nrm);
                y0 = m0 * rn; y1 = m1 * rn;
            }
            if (is_even) nu += (float)bit; else nd += (float)bit;
            amp *= bit ? y1 : y0;
            phs += bit ? ph1 : ph0;
        }
    }

    if (wv < 4 && q == 0) {
        int eg = ebg + eh;
        if (eg < nbatch) {
            float s, c;
            sincosf(phs, &s, &c);
            out[eg]          = amp * c;
            out[nbatch + eg] = amp * s;
        }
    }
}

extern "C" void kernel_launch(void* const* d_in, const int* in_sizes, int n_in,
                              void* d_out, int out_size, void* d_ws, size_t ws_size,
                              hipStream_t stream) {
    const int*   x     = (const int*)  d_in[0];
    const float* w_ih0 = (const float*)d_in[1];
    const float* w_hh0 = (const float*)d_in[2];
    const float* w_ih1 = (const float*)d_in[3];
    const float* w_hh1 = (const float*)d_in[4];
    const float* w_lin = (const float*)d_in[5];
    const float* b_lin = (const float*)d_in[6];
    float* out = (float*)d_out;
    _Float16* wsp = (_Float16*)d_ws;

    const int nbatch = in_sizes[0] / 64;

    prep_kernel<<<384, 256, 0, stream>>>(w_hh0, w_ih1, w_hh1, wsp);

    const int blocks = (nbatch + 63) / 64;
    rnn_wf_pipe<<<blocks, 512, 0, stream>>>(x, w_ih0, w_lin, b_lin, wsp, out, nbatch);
}